// Round 9
// baseline (426.170 us; speedup 1.0000x reference)
//
#include <hip/hip_runtime.h>
#include <math.h>

#define TOKENS 16384
#define DMODEL 2048
#define NEXP   256
#define TOPK   8
#define BM     32               // tokens per block
#define FBM    32               // fallback tile
#define NTIL   (DMODEL / 32)    // 64 k-tiles

typedef _Float16 f16;
typedef _Float16 f16x8 __attribute__((ext_vector_type(8)));
typedef float    f32x4 __attribute__((ext_vector_type(4)));

// ---------------- prep: w (E x D f32) -> fp16 split planes, tile-major; zero counts/ctr ----------------
// plane layout: idx = t*(NEXP*32) + e*32 + ki   (t = d>>5, ki = d&31); 8 elems/thread
__global__ void k_prep(const float* __restrict__ w,
                       f16* __restrict__ wsH, f16* __restrict__ wsL,
                       float* __restrict__ counts, unsigned* __restrict__ ctr) {
    const int tid = threadIdx.x;
    if (blockIdx.x == 0) {
        counts[tid] = 0.0f;
        if (tid == 0 && ctr) *ctr = 0u;
    }
    const int g8 = (blockIdx.x * 256 + tid) * 8;
    const int ki = g8 & 31;
    const int e  = (g8 >> 5) & 255;
    const int t  = g8 >> 13;
    const float* src = w + (size_t)e * DMODEL + t * 32 + ki;
    f16x8 hv, lv;
#pragma unroll
    for (int i = 0; i < 8; i++) {
        float v = src[i] * 64.0f;
        f16 h = (f16)v;
        hv[i] = h;
        lv[i] = (f16)((v - (float)h) * 2048.0f);
    }
    *(f16x8*)(wsH + g8) = hv;
    *(f16x8*)(wsL + g8) = lv;
}

__global__ void k_zero(float* __restrict__ counts) {
    counts[threadIdx.x] = 0.0f;
}

// ---------------- main: barrier-free per-wave GEMM (A from global, no LDS in k-loop) ----------------
// 8 waves/block; wave wv owns experts wv*32..wv*32+31 over the block's 32 tokens.
__global__ __launch_bounds__(512, 4) void k_main(
        const float* __restrict__ x,
        const f16*   __restrict__ wh,
        const f16*   __restrict__ wl,
        const float* __restrict__ bias,
        float* __restrict__ out,
        unsigned* __restrict__ ctr) {
    __shared__ float logits[BM][NEXP];      // 32 KB (epilogue only)
    __shared__ float hist[NEXP];
    __shared__ unsigned lastflag;

    const int tid  = threadIdx.x;
    const int tok0 = blockIdx.x * BM;
    const int lane = tid & 63;
    const int wv   = tid >> 6;              // 0..7
    const int eb   = lane & 15;
    const int kq   = lane >> 4;             // 0..3

    if (tid < NEXP) hist[tid] = 0.0f;

    // A source rows: lane (eb,kq) reads x[tok0 + m*16 + eb][t*32 + kq*8 .. +7]
    const float* xr0 = x + (size_t)(tok0 + eb) * DMODEL + kq * 8;
    const float* xr1 = xr0 + (size_t)16 * DMODEL;
    // B fragment offsets within a k-tile (halfs)
    const int bo0 = (wv * 32 + eb) * 32 + kq * 8;
    const int bo1 = bo0 + 512;

    f32x4 c000 = {0,0,0,0}, c001 = {0,0,0,0}, c010 = {0,0,0,0}, c011 = {0,0,0,0};
    f32x4 c100 = {0,0,0,0}, c101 = {0,0,0,0}, c110 = {0,0,0,0}, c111 = {0,0,0,0};

    f32x4 Aa, Ab, Ac, Ad;                                   // x(t) fp32 staging
    f16x8 B0h0, B0h1, B0l0, B0l1, B1h0, B1h1, B1l0, B1l1;   // B double buffer
    f16x8 a0h, a0l, a1h, a1l;                               // A fragments

#define LOADA(T) do {                                         \
    const float* _p0 = xr0 + (size_t)(T) * 32;                \
    const float* _p1 = xr1 + (size_t)(T) * 32;                \
    Aa = *(const f32x4*)_p0;  Ab = *(const f32x4*)(_p0 + 4);  \
    Ac = *(const f32x4*)_p1;  Ad = *(const f32x4*)(_p1 + 4);  \
} while (0)

#define LOADB(P, T) do {                                      \
    const f16* _ph = wh + (size_t)(T) * (NEXP * 32);          \
    const f16* _pl = wl + (size_t)(T) * (NEXP * 32);          \
    P##h0 = *(const f16x8*)(_ph + bo0);                       \
    P##h1 = *(const f16x8*)(_ph + bo1);                       \
    P##l0 = *(const f16x8*)(_pl + bo0);                       \
    P##l1 = *(const f16x8*)(_pl + bo1);                       \
} while (0)

#define CVT1(H, L, I, V) { f16 _t = (f16)(V); H[I] = _t; L[I] = (f16)(((V) - (float)_t) * 2048.0f); }
#define CVT8(DH, DL, VA, VB) do {                             \
    f16x8 _h, _l;                                             \
    CVT1(_h, _l, 0, VA[0]) CVT1(_h, _l, 1, VA[1])             \
    CVT1(_h, _l, 2, VA[2]) CVT1(_h, _l, 3, VA[3])             \
    CVT1(_h, _l, 4, VB[0]) CVT1(_h, _l, 5, VB[1])             \
    CVT1(_h, _l, 6, VB[2]) CVT1(_h, _l, 7, VB[3])             \
    DH = _h; DL = _l;                                         \
} while (0)
#define CVTA() do { CVT8(a0h, a0l, Aa, Ab); CVT8(a1h, a1l, Ac, Ad); } while (0)

#define MFMA_ __builtin_amdgcn_mfma_f32_16x16x32_f16
#define COMPUTE(P) do {                                       \
    __builtin_amdgcn_s_setprio(1);                            \
    c000 = MFMA_(a0h, P##h0, c000, 0, 0, 0);                  \
    c001 = MFMA_(a0h, P##h1, c001, 0, 0, 0);                  \
    c010 = MFMA_(a1h, P##h0, c010, 0, 0, 0);                  \
    c011 = MFMA_(a1h, P##h1, c011, 0, 0, 0);                  \
    c100 = MFMA_(a0l, P##h0, c100, 0, 0, 0);                  \
    c101 = MFMA_(a0l, P##h1, c101, 0, 0, 0);                  \
    c110 = MFMA_(a1l, P##h0, c110, 0, 0, 0);                  \
    c111 = MFMA_(a1l, P##h1, c111, 0, 0, 0);                  \
    c100 = MFMA_(a0h, P##l0, c100, 0, 0, 0);                  \
    c101 = MFMA_(a0h, P##l1, c101, 0, 0, 0);                  \
    c110 = MFMA_(a1h, P##l0, c110, 0, 0, 0);                  \
    c111 = MFMA_(a1h, P##l1, c111, 0, 0, 0);                  \
    __builtin_amdgcn_s_setprio(0);                            \
} while (0)

    // prologue: tile 0 in flight
    LOADA(0);
    LOADB(B0, 0);

    // barrier-free k-loop: waves drift freely; loads pipelined ~1 tile deep per wave
#pragma unroll 1
    for (int t = 0; t < NTIL; t += 2) {
        CVTA();                         // consume A(t) -> frags
        LOADA(t + 1);                   // t+1 <= 63 always
        LOADB(B1, t + 1);
        COMPUTE(B0);                    // tile t
        CVTA();                         // consume A(t+1) -> frags
        if (t + 2 < NTIL) {
            LOADA(t + 2);
            LOADB(B0, t + 2);
        }
        COMPUTE(B1);                    // tile t+1
    }
#undef LOADA
#undef LOADB
#undef CVT1
#undef CVT8
#undef CVTA
#undef COMPUTE

    // ---- epilogue: descale + bias, write logits (C layout: col=lane&15, row=(lane>>4)*4+i) ----
#define EPI(C0, C1, M, N) do {                                                        \
    const int _e = wv * 32 + (N) * 16 + eb;                                           \
    const float _b = bias[_e];                                                        \
    logits[(M) * 16 + kq * 4 + 0][_e] = (C0[0] + C1[0] * (1.0f/2048.0f)) * (1.0f/64.0f) + _b; \
    logits[(M) * 16 + kq * 4 + 1][_e] = (C0[1] + C1[1] * (1.0f/2048.0f)) * (1.0f/64.0f) + _b; \
    logits[(M) * 16 + kq * 4 + 2][_e] = (C0[2] + C1[2] * (1.0f/2048.0f)) * (1.0f/64.0f) + _b; \
    logits[(M) * 16 + kq * 4 + 3][_e] = (C0[3] + C1[3] * (1.0f/2048.0f)) * (1.0f/64.0f) + _b; \
} while (0)
    EPI(c000, c100, 0, 0);
    EPI(c001, c101, 0, 1);
    EPI(c010, c110, 1, 0);
    EPI(c011, c111, 1, 1);
#undef EPI
    __syncthreads();

    // ---- top-8 per token; each wave handles 4 tokens (verbatim from passing kernel) ----
    for (int tt = 0; tt < 4; tt++) {
        const int tok = wv * 4 + tt;
        float4 v4 = *(const float4*)&logits[tok][lane * 4];
        float lv[4] = {v4.x, v4.y, v4.z, v4.w};
        int msk = 0xF;
        float topv[TOPK];
        int   topi[TOPK];
#pragma unroll
        for (int r = 0; r < TOPK; r++) {
            float bvv = -INFINITY;
            int   bii = 0x7fffffff;
#pragma unroll
            for (int j = 0; j < 4; j++) {
                if (msk & (1 << j)) {
                    float vv = lv[j];
                    int   ii = lane * 4 + j;
                    if (vv > bvv || (vv == bvv && ii < bii)) { bvv = vv; bii = ii; }
                }
            }
#pragma unroll
            for (int off = 32; off > 0; off >>= 1) {
                float ov = __shfl_xor(bvv, off);
                int   oi = __shfl_xor(bii, off);
                if (ov > bvv || (ov == bvv && oi < bii)) { bvv = ov; bii = oi; }
            }
            topv[r] = bvv;
            topi[r] = bii;
            if ((bii >> 2) == lane) msk &= ~(1 << (bii & 3));
        }
        float m = topv[0];
        float s = 0.0f;
#pragma unroll
        for (int r = 0; r < TOPK; r++) s += expf(topv[r] - m);

        const int gtok = tok0 + tok;
        if (lane < TOPK) {
            out[(size_t)gtok * TOPK + lane] = expf(topv[lane] - m) / s;
        } else if (lane < 2 * TOPK) {
            int r = lane - TOPK;
            out[(size_t)TOKENS * TOPK + (size_t)gtok * TOPK + r] = (float)topi[r];
            atomicAdd(&hist[topi[r]], 1.0f);
        }
    }
    __syncthreads();
    if (tid < NEXP) {
        float hv = hist[tid];
        if (hv != 0.0f) atomicAdd(&out[(size_t)2 * TOKENS * TOPK + tid], hv);
    }

    // ---- fused stats: last block to finish computes them ----
    if (ctr) {
        __threadfence();
        if (tid == 0) {
            unsigned d = atomicAdd(ctr, 1u);
            lastflag = (d == gridDim.x - 1) ? 1u : 0u;
        }
        __syncthreads();
        if (lastflag) {
            float* counts = out + (size_t)2 * TOKENS * TOPK;
            float c = (tid < NEXP) ? *(volatile float*)&counts[tid] : 0.0f;
            float* sm = hist;
            if (tid < NEXP) sm[tid] = c;
            __syncthreads();
            for (int s = 128; s > 0; s >>= 1) {
                if (tid < s) sm[tid] += sm[tid + s];
                __syncthreads();
            }
            float mean = sm[0] / (float)NEXP;
            __syncthreads();
            if (tid < NEXP) { float d2 = c - mean; sm[tid] = d2 * d2; }
            __syncthreads();
            for (int s = 128; s > 0; s >>= 1) {
                if (tid < s) sm[tid] += sm[tid + s];
                __syncthreads();
            }
            float var = sm[0] / (float)(NEXP - 1);
            __syncthreads();
            if (tid < NEXP) sm[tid] = c;
            __syncthreads();
            for (int s = 128; s > 0; s >>= 1) {
                if (tid < s) sm[tid] = fmaxf(sm[tid], sm[tid + s]);
                __syncthreads();
            }
            float mx = sm[0];
            __syncthreads();
            if (tid < NEXP) sm[tid] = c;
            __syncthreads();
            for (int s = 128; s > 0; s >>= 1) {
                if (tid < s) sm[tid] = fminf(sm[tid], sm[tid + s]);
                __syncthreads();
            }
            float mn = sm[0];
            if (tid == 0) {
                float* scal = counts + NEXP;
                scal[0] = sqrtf(var) / (mean + 1e-6f);
                scal[1] = mx;
                scal[2] = mn;
                scal[3] = (float)(TOKENS * TOPK) / (float)NEXP;
            }
        }
    }
}

// ---------------- fallback (no workspace): fp32 VALU kernel (32-token tile) ----------------
__global__ __launch_bounds__(256, 3) void k_main_fb(
        const float* __restrict__ x,
        const float* __restrict__ wsrc,
        const float* __restrict__ bias,
        float* __restrict__ out) {
    __shared__ float xT[16][FBM];
    __shared__ float wS[16][NEXP];
    __shared__ float logits[FBM][NEXP];
    __shared__ float hist[NEXP];

    const int tid  = threadIdx.x;
    const int tok0 = blockIdx.x * FBM;
    const int ty   = tid >> 5;
    const int tx   = tid & 31;

    hist[tid] = 0.0f;

    float acc[4][8];
#pragma unroll
    for (int i = 0; i < 4; i++)
#pragma unroll
        for (int j = 0; j < 8; j++) acc[i][j] = 0.0f;

    const int lx_tok = tid >> 3;
    const int lx_d   = (tid & 7) * 2;

    for (int k0 = 0; k0 < DMODEL; k0 += 16) {
        __syncthreads();
        float2 xv = *(const float2*)&x[(size_t)(tok0 + lx_tok) * DMODEL + k0 + lx_d];
        xT[lx_d][lx_tok]     = xv.x;
        xT[lx_d + 1][lx_tok] = xv.y;
#pragma unroll
        for (int i = 0; i < 16; i++)
            wS[i][tid] = wsrc[(size_t)tid * DMODEL + k0 + i];
        __syncthreads();
#pragma unroll
        for (int k = 0; k < 16; k++) {
            float4 a  = *(const float4*)&xT[k][ty * 4];
            float4 b0 = *(const float4*)&wS[k][tx * 8];
            float4 b1 = *(const float4*)&wS[k][tx * 8 + 4];
            float av[4] = {a.x, a.y, a.z, a.w};
            float bv[8] = {b0.x, b0.y, b0.z, b0.w, b1.x, b1.y, b1.z, b1.w};
#pragma unroll
            for (int i = 0; i < 4; i++)
#pragma unroll
                for (int j = 0; j < 8; j++)
                    acc[i][j] = fmaf(av[i], bv[j], acc[i][j]);
        }
    }

    float bb[8];
#pragma unroll
    for (int j = 0; j < 8; j++) bb[j] = bias[tx * 8 + j];
#pragma unroll
    for (int i = 0; i < 4; i++) {
#pragma unroll
        for (int j = 0; j < 8; j++)
            logits[ty * 4 + i][tx * 8 + j] = acc[i][j] + bb[j];
    }
    __syncthreads();

    const int lane = tid & 63;
    const int wv   = tid >> 6;
    for (int tt = 0; tt < 8; tt++) {
        const int tok = wv * 8 + tt;
        float4 v4 = *(const float4*)&logits[tok][lane * 4];
        float lv[4] = {v4.x, v4.y, v4.z, v4.w};
        int msk = 0xF;
        float topv[TOPK];
        int   topi[TOPK];
#pragma unroll
        for (int r = 0; r < TOPK; r++) {
            float bvv = -INFINITY;
            int   bii = 0x7fffffff;
#pragma unroll
            for (int j = 0; j < 4; j++) {
                if (msk & (1 << j)) {
                    float vv = lv[j];
                    int   ii = lane * 4 + j;
                    if (vv > bvv || (vv == bvv && ii < bii)) { bvv = vv; bii = ii; }
                }
            }
#pragma unroll
            for (int off = 32; off > 0; off >>= 1) {
                float ov = __shfl_xor(bvv, off);
                int   oi = __shfl_xor(bii, off);
                if (ov > bvv || (ov == bvv && oi < bii)) { bvv = ov; bii = oi; }
            }
            topv[r] = bvv;
            topi[r] = bii;
            if ((bii >> 2) == lane) msk &= ~(1 << (bii & 3));
        }
        float m = topv[0];
        float s = 0.0f;
#pragma unroll
        for (int r = 0; r < TOPK; r++) s += expf(topv[r] - m);

        const int gtok = tok0 + tok;
        if (lane < TOPK) {
            out[(size_t)gtok * TOPK + lane] = expf(topv[lane] - m) / s;
        } else if (lane < 2 * TOPK) {
            int r = lane - TOPK;
            out[(size_t)TOKENS * TOPK + (size_t)gtok * TOPK + r] = (float)topi[r];
            atomicAdd(&hist[topi[r]], 1.0f);
        }
    }
    __syncthreads();
    float hv = hist[tid];
    if (hv != 0.0f) atomicAdd(&out[(size_t)2 * TOKENS * TOPK + tid], hv);
}

// ---------------- stats kernel (used when ws has no room for the done-counter) ----------------
__global__ void k_stats(float* __restrict__ out) {
    __shared__ float sm[NEXP];
    const float* counts = out + (size_t)2 * TOKENS * TOPK;
    const int t = threadIdx.x;
    float c = counts[t];

    sm[t] = c;
    __syncthreads();
    for (int s = 128; s > 0; s >>= 1) {
        if (t < s) sm[t] += sm[t + s];
        __syncthreads();
    }
    float mean = sm[0] / (float)NEXP;
    __syncthreads();

    float d = c - mean;
    sm[t] = d * d;
    __syncthreads();
    for (int s = 128; s > 0; s >>= 1) {
        if (t < s) sm[t] += sm[t + s];
        __syncthreads();
    }
    float var = sm[0] / (float)(NEXP - 1);
    __syncthreads();

    sm[t] = c;
    __syncthreads();
    for (int s = 128; s > 0; s >>= 1) {
        if (t < s) sm[t] = fmaxf(sm[t], sm[t + s]);
        __syncthreads();
    }
    float mx = sm[0];
    __syncthreads();

    sm[t] = c;
    __syncthreads();
    for (int s = 128; s > 0; s >>= 1) {
        if (t < s) sm[t] = fminf(sm[t], sm[t + s]);
        __syncthreads();
    }
    float mn = sm[0];

    if (t == 0) {
        float* scal = out + (size_t)2 * TOKENS * TOPK + NEXP;
        scal[0] = sqrtf(var) / (mean + 1e-6f);
        scal[1] = mx;
        scal[2] = mn;
        scal[3] = (float)(TOKENS * TOPK) / (float)NEXP;
    }
}

extern "C" void kernel_launch(void* const* d_in, const int* in_sizes, int n_in,
                              void* d_out, int out_size, void* d_ws, size_t ws_size,
                              hipStream_t stream) {
    const float* x    = (const float*)d_in[0];
    const float* w    = (const float*)d_in[1];
    const float* bias = (const float*)d_in[2];
    float* out = (float*)d_out;
    float* counts = out + (size_t)2 * TOKENS * TOPK;

    const size_t need = (size_t)DMODEL * NEXP * 2 * sizeof(_Float16);  // 2 MB
    if (ws_size >= need) {
        f16* wsH = (f16*)d_ws;
        f16* wsL = wsH + (size_t)DMODEL * NEXP;
        unsigned* ctr = (ws_size >= need + 64)
                            ? (unsigned*)((char*)d_ws + need) : (unsigned*)0;
        k_prep<<<(DMODEL * NEXP) / (256 * 8), 256, 0, stream>>>(w, wsH, wsL, counts, ctr);
        k_main<<<TOKENS / BM, 512, 0, stream>>>(x, wsH, wsL, bias, out, ctr);
        if (!ctr) k_stats<<<1, NEXP, 0, stream>>>(out);
    } else {
        k_zero<<<1, NEXP, 0, stream>>>(counts);
        k_main_fb<<<TOKENS / FBM, 256, 0, stream>>>(x, w, bias, out);
        k_stats<<<1, NEXP, 0, stream>>>(out);
    }
}

// Round 10
// 367.014 us; speedup vs baseline: 1.1612x; 1.1612x over previous
//
#include <hip/hip_runtime.h>
#include <math.h>

#define TOKENS 16384
#define DMODEL 2048
#define NEXP   256
#define TOPK   8
#define BM     32               // tokens per block (new kernel)
#define FBM    32               // fallback tile
#define NTIL   (DMODEL / 32)    // 64 k-tiles
// R6-fallback constants
#define KC     256
#define NCH    (DMODEL / KC)
#define RS     264

typedef _Float16 f16;
typedef _Float16 f16x8 __attribute__((ext_vector_type(8)));
typedef _Float16 f16x4 __attribute__((ext_vector_type(4)));
typedef float    f32x4 __attribute__((ext_vector_type(4)));

#define BAR() asm volatile("s_waitcnt lgkmcnt(0)\ns_barrier" ::: "memory")

// ---------------- prep W: w (E x D f32) -> fp16 split planes, tile-major; zero counts/ctr ----------------
__global__ void k_prep(const float* __restrict__ w,
                       f16* __restrict__ wsH, f16* __restrict__ wsL,
                       float* __restrict__ counts, unsigned* __restrict__ ctr) {
    const int tid = threadIdx.x;
    if (blockIdx.x == 0) {
        counts[tid] = 0.0f;
        if (tid == 0 && ctr) *ctr = 0u;
    }
    const int g8 = (blockIdx.x * 256 + tid) * 8;
    const int ki = g8 & 31;
    const int e  = (g8 >> 5) & 255;
    const int t  = g8 >> 13;
    const float* src = w + (size_t)e * DMODEL + t * 32 + ki;
    f16x8 hv, lv;
#pragma unroll
    for (int i = 0; i < 8; i++) {
        float v = src[i] * 64.0f;
        f16 h = (f16)v;
        hv[i] = h;
        lv[i] = (f16)((v - (float)h) * 2048.0f);
    }
    *(f16x8*)(wsH + g8) = hv;
    *(f16x8*)(wsL + g8) = lv;
}

// ---------------- prep X: x (fp32 row-major) -> xs split-f16, tile-major per 32-token block ----------------
// xs layout per (blk b, tile t): 2048 halfs = hi[32 tok][32 k] then lo[32][32]; stride 4 KB.
__global__ void k_prep_x(const float* __restrict__ x, f16* __restrict__ xs) {
    const int p   = blockIdx.x;          // 0..16383
    const int b   = p >> 5;              // 0..511
    const int tt0 = (p & 31) * 2;        // tile pair
    const int i   = threadIdx.x;         // 0..255
    const int tile = tt0 + (i >> 7);
    const int r    = i & 127;
    const int tok  = r >> 2;             // 0..31
    const int k8   = (r & 3) * 8;        // 0,8,16,24
    const float* src = x + (size_t)(b * 32 + tok) * DMODEL + tile * 32 + k8;
    f32x4 v0 = *(const f32x4*)src;
    f32x4 v1 = *(const f32x4*)(src + 4);
    f16x8 hv, lv;
#pragma unroll
    for (int j = 0; j < 4; j++) {
        float v = v0[j];
        f16 h = (f16)v;
        hv[j] = h;
        lv[j] = (f16)((v - (float)h) * 2048.0f);
    }
#pragma unroll
    for (int j = 0; j < 4; j++) {
        float v = v1[j];
        f16 h = (f16)v;
        hv[4 + j] = h;
        lv[4 + j] = (f16)((v - (float)h) * 2048.0f);
    }
    f16* dst = xs + (size_t)(b * 64 + tile) * 2048 + tok * 32 + k8;
    *(f16x8*)dst          = hv;
    *(f16x8*)(dst + 1024) = lv;
}

__global__ void k_zero(float* __restrict__ counts) {
    counts[threadIdx.x] = 0.0f;
}

// ---------------- main: register-direct barrier-free GEMM from tile-major xs + w planes ----------------
// 4 waves; wave wv owns experts wv*64..wv*64+63 (R1 decomposition). No LDS/barriers/cvt in k-loop.
__global__ __launch_bounds__(256) void k_main(
        const f16* __restrict__ xs,
        const f16* __restrict__ wh,
        const f16* __restrict__ wl,
        const float* __restrict__ bias,
        float* __restrict__ out,
        unsigned* __restrict__ ctr) {
    __shared__ float logits[BM][NEXP];      // epilogue only
    __shared__ float hist[NEXP];
    __shared__ unsigned lastflag;

    const int tid  = threadIdx.x;
    const int tok0 = blockIdx.x * BM;
    const int lane = tid & 63;
    const int wv   = tid >> 6;              // 0..3
    const int eb   = lane & 15;
    const int kq   = lane >> 4;             // 0..3

    hist[tid] = 0.0f;

    const f16* xsb = xs + (size_t)blockIdx.x * (NTIL * 2048);
    const int ao  = eb * 32 + kq * 8;       // halfs within a tile's hi plane
    const int bo0 = ((wv * 4 + 0) * 16 + eb) * 32 + kq * 8;
    const int bo1 = ((wv * 4 + 1) * 16 + eb) * 32 + kq * 8;
    const int bo2 = ((wv * 4 + 2) * 16 + eb) * 32 + kq * 8;
    const int bo3 = ((wv * 4 + 3) * 16 + eb) * 32 + kq * 8;

    f32x4 acc0[2][4], acc1[2][4];
#pragma unroll
    for (int m = 0; m < 2; m++)
#pragma unroll
        for (int q = 0; q < 4; q++) {
            acc0[m][q] = (f32x4){0.0f, 0.0f, 0.0f, 0.0f};
            acc1[m][q] = (f32x4){0.0f, 0.0f, 0.0f, 0.0f};
        }

    // named double-buffer register sets P0 / P1
    f16x8 P0a0h, P0a1h, P0a0l, P0a1l, P1a0h, P1a1h, P1a0l, P1a1l;
    f16x8 P0bh0, P0bh1, P0bh2, P0bh3, P0bl0, P0bl1, P0bl2, P0bl3;
    f16x8 P1bh0, P1bh1, P1bh2, P1bh3, P1bl0, P1bl1, P1bl2, P1bl3;

#define LOADA(S, T) do {                                              \
    const f16* _p = xsb + (size_t)(T) * 2048 + ao;                    \
    S##a0h = *(const f16x8*)_p;                                       \
    S##a1h = *(const f16x8*)(_p + 512);                               \
    S##a0l = *(const f16x8*)(_p + 1024);                              \
    S##a1l = *(const f16x8*)(_p + 1536);                              \
} while (0)

#define LOADB(S, T) do {                                              \
    const f16* _ph = wh + (size_t)(T) * (NEXP * 32);                  \
    const f16* _pl = wl + (size_t)(T) * (NEXP * 32);                  \
    S##bh0 = *(const f16x8*)(_ph + bo0);                              \
    S##bh1 = *(const f16x8*)(_ph + bo1);                              \
    S##bh2 = *(const f16x8*)(_ph + bo2);                              \
    S##bh3 = *(const f16x8*)(_ph + bo3);                              \
    S##bl0 = *(const f16x8*)(_pl + bo0);                              \
    S##bl1 = *(const f16x8*)(_pl + bo1);                              \
    S##bl2 = *(const f16x8*)(_pl + bo2);                              \
    S##bl3 = *(const f16x8*)(_pl + bo3);                              \
} while (0)

#define M_(A, B, C) __builtin_amdgcn_mfma_f32_16x16x32_f16(A, B, C, 0, 0, 0)
#define CQ(S, BH, BL, q) do {                                         \
    acc0[0][q] = M_(S##a0h, S##BH, acc0[0][q]);                       \
    acc0[1][q] = M_(S##a1h, S##BH, acc0[1][q]);                       \
    acc1[0][q] = M_(S##a0l, S##BH, acc1[0][q]);                       \
    acc1[1][q] = M_(S##a1l, S##BH, acc1[1][q]);                       \
    acc1[0][q] = M_(S##a0h, S##BL, acc1[0][q]);                       \
    acc1[1][q] = M_(S##a1h, S##BL, acc1[1][q]);                       \
} while (0)
#define COMPUTE(S) do {                                               \
    __builtin_amdgcn_s_setprio(1);                                    \
    CQ(S, bh0, bl0, 0); CQ(S, bh1, bl1, 1);                           \
    CQ(S, bh2, bl2, 2); CQ(S, bh3, bl3, 3);                           \
    __builtin_amdgcn_s_setprio(0);                                    \
} while (0)

    LOADA(P0, 0);
    LOADB(P0, 0);
#pragma unroll 1
    for (int t = 0; t < NTIL; t += 2) {
        LOADA(P1, t + 1);
        LOADB(P1, t + 1);
        COMPUTE(P0);
        if (t + 2 < NTIL) {
            LOADA(P0, t + 2);
            LOADB(P0, t + 2);
        }
        COMPUTE(P1);
    }
#undef LOADA
#undef LOADB
#undef M_
#undef CQ
#undef COMPUTE

    // ---- epilogue: descale + bias, write logits (C layout: col=lane&15, row=(lane>>4)*4+i) ----
#pragma unroll
    for (int m = 0; m < 2; m++) {
#pragma unroll
        for (int q = 0; q < 4; q++) {
            const int e = (wv * 4 + q) * 16 + eb;
            const float b = bias[e];
#pragma unroll
            for (int i = 0; i < 4; i++) {
                const int tk = m * 16 + kq * 4 + i;
                logits[tk][e] = (acc0[m][q][i] + acc1[m][q][i] * (1.0f / 2048.0f)) * (1.0f / 64.0f) + b;
            }
        }
    }
    __syncthreads();

    // ---- top-8 per token; each wave handles 8 tokens (verbatim from passing kernel) ----
    for (int tt = 0; tt < 8; tt++) {
        const int tok = wv * 8 + tt;
        float4 v4 = *(const float4*)&logits[tok][lane * 4];
        float lv[4] = {v4.x, v4.y, v4.z, v4.w};
        int msk = 0xF;
        float topv[TOPK];
        int   topi[TOPK];
#pragma unroll
        for (int r = 0; r < TOPK; r++) {
            float bvv = -INFINITY;
            int   bii = 0x7fffffff;
#pragma unroll
            for (int j = 0; j < 4; j++) {
                if (msk & (1 << j)) {
                    float vv = lv[j];
                    int   ii = lane * 4 + j;
                    if (vv > bvv || (vv == bvv && ii < bii)) { bvv = vv; bii = ii; }
                }
            }
#pragma unroll
            for (int off = 32; off > 0; off >>= 1) {
                float ov = __shfl_xor(bvv, off);
                int   oi = __shfl_xor(bii, off);
                if (ov > bvv || (ov == bvv && oi < bii)) { bvv = ov; bii = oi; }
            }
            topv[r] = bvv;
            topi[r] = bii;
            if ((bii >> 2) == lane) msk &= ~(1 << (bii & 3));
        }
        float m = topv[0];
        float s = 0.0f;
#pragma unroll
        for (int r = 0; r < TOPK; r++) s += expf(topv[r] - m);

        const int gtok = tok0 + tok;
        if (lane < TOPK) {
            out[(size_t)gtok * TOPK + lane] = expf(topv[lane] - m) / s;
        } else if (lane < 2 * TOPK) {
            int r = lane - TOPK;
            out[(size_t)TOKENS * TOPK + (size_t)gtok * TOPK + r] = (float)topi[r];
            atomicAdd(&hist[topi[r]], 1.0f);
        }
    }
    __syncthreads();
    float hv = hist[tid];
    if (hv != 0.0f) atomicAdd(&out[(size_t)2 * TOKENS * TOPK + tid], hv);

    // ---- fused stats: last block to finish computes them ----
    if (ctr) {
        __threadfence();
        if (tid == 0) {
            unsigned d = atomicAdd(ctr, 1u);
            lastflag = (d == gridDim.x - 1) ? 1u : 0u;
        }
        __syncthreads();
        if (lastflag) {
            float* counts = out + (size_t)2 * TOKENS * TOPK;
            float c = *(volatile float*)&counts[tid];
            float* sm = hist;
            sm[tid] = c;
            __syncthreads();
            for (int s = 128; s > 0; s >>= 1) {
                if (tid < s) sm[tid] += sm[tid + s];
                __syncthreads();
            }
            float mean = sm[0] / (float)NEXP;
            __syncthreads();
            float d2 = c - mean;
            sm[tid] = d2 * d2;
            __syncthreads();
            for (int s = 128; s > 0; s >>= 1) {
                if (tid < s) sm[tid] += sm[tid + s];
                __syncthreads();
            }
            float var = sm[0] / (float)(NEXP - 1);
            __syncthreads();
            sm[tid] = c;
            __syncthreads();
            for (int s = 128; s > 0; s >>= 1) {
                if (tid < s) sm[tid] = fmaxf(sm[tid], sm[tid + s]);
                __syncthreads();
            }
            float mx = sm[0];
            __syncthreads();
            sm[tid] = c;
            __syncthreads();
            for (int s = 128; s > 0; s >>= 1) {
                if (tid < s) sm[tid] = fminf(sm[tid], sm[tid + s]);
                __syncthreads();
            }
            float mn = sm[0];
            if (tid == 0) {
                float* scal = counts + NEXP;
                scal[0] = sqrtf(var) / (mean + 1e-6f);
                scal[1] = mx;
                scal[2] = mn;
                scal[3] = (float)(TOKENS * TOPK) / (float)NEXP;
            }
        }
    }
}

// ---------------- mid-fallback (ws has 2MB but not 130MB): R6 8-wave LDS kernel (passed, 178 µs) ----------------
__global__ __launch_bounds__(512, 4) void k_main_lds(
        const float* __restrict__ x,
        const f16*   __restrict__ wh,
        const f16*   __restrict__ wl,
        const float* __restrict__ bias,
        float* __restrict__ out,
        unsigned* __restrict__ ctr) {
    __shared__ __align__(16) char raw[2 * BM * RS * sizeof(f16)];
    __shared__ float hist[NEXP];
    __shared__ unsigned lastflag;

    f16* AH = (f16*)raw;
    f16* AL = AH + BM * RS;
    float (*logits)[NEXP] = (float (*)[NEXP])raw;

    const int tid  = threadIdx.x;
    const int tok0 = blockIdx.x * BM;
    const int lane = tid & 63;
    const int wv   = tid >> 6;
    const int eb   = lane & 15;
    const int kq   = lane >> 4;

    if (tid < NEXP) hist[tid] = 0.0f;

    const int s_tok  = tid >> 4;
    const int s_lane = tid & 15;
    const float* xb = x + (size_t)(tok0 + s_tok) * DMODEL + s_lane * 4;
    const int wbase = s_tok * RS + s_lane * 4;

    const int ro0 = eb * RS + kq * 8;
    const int ro1 = (16 + eb) * RS + kq * 8;
    const size_t bo0 = (size_t)((wv * 32 + eb) * 32 + kq * 8);
    const size_t bo1 = (size_t)((wv * 32 + 16 + eb) * 32 + kq * 8);

    f32x4 acc0[2][2], acc1[2][2];
#pragma unroll
    for (int m = 0; m < 2; m++)
#pragma unroll
        for (int n = 0; n < 2; n++) {
            acc0[m][n] = (f32x4){0.0f, 0.0f, 0.0f, 0.0f};
            acc1[m][n] = (f32x4){0.0f, 0.0f, 0.0f, 0.0f};
        }

    f32x4 xr[4];
#pragma unroll
    for (int s = 0; s < 4; s++) xr[s] = *(const f32x4*)(xb + s * 64);
#pragma unroll
    for (int s = 0; s < 4; s++) {
        f32x4 v = xr[s];
        f16 h0 = (f16)v.x, h1 = (f16)v.y, h2 = (f16)v.z, h3 = (f16)v.w;
        f16x4 hv = {h0, h1, h2, h3};
        f16x4 lv = {(f16)((v.x - (float)h0) * 2048.0f),
                    (f16)((v.y - (float)h1) * 2048.0f),
                    (f16)((v.z - (float)h2) * 2048.0f),
                    (f16)((v.w - (float)h3) * 2048.0f)};
        *(f16x4*)(AH + wbase + s * 64) = hv;
        *(f16x4*)(AL + wbase + s * 64) = lv;
    }
    f16x8 bh0 = *(const f16x8*)(wh + bo0);
    f16x8 bh1 = *(const f16x8*)(wh + bo1);
    f16x8 bl0 = *(const f16x8*)(wl + bo0);
    f16x8 bl1 = *(const f16x8*)(wl + bo1);
    BAR();

#pragma unroll 1
    for (int c = 0; c < NCH; ++c) {
        if (c < NCH - 1) {
#pragma unroll
            for (int s = 0; s < 4; s++)
                xr[s] = *(const f32x4*)(xb + (c + 1) * KC + s * 64);
        }
#pragma unroll
        for (int j = 0; j < 8; ++j) {
            const int t = c * 8 + j;
            f16x8 nh0, nh1, nl0, nl1;
            if (t < NTIL - 1) {
                const f16* pb = wh + (size_t)(t + 1) * (NEXP * 32);
                const f16* pl = wl + (size_t)(t + 1) * (NEXP * 32);
                nh0 = *(const f16x8*)(pb + bo0);
                nh1 = *(const f16x8*)(pb + bo1);
                nl0 = *(const f16x8*)(pl + bo0);
                nl1 = *(const f16x8*)(pl + bo1);
            }
            const int co = j * 32;
            f16x8 a0h = *(const f16x8*)(AH + ro0 + co);
            f16x8 a1h = *(const f16x8*)(AH + ro1 + co);
            f16x8 a0l = *(const f16x8*)(AL + ro0 + co);
            f16x8 a1l = *(const f16x8*)(AL + ro1 + co);

            __builtin_amdgcn_s_setprio(1);
            acc0[0][0] = __builtin_amdgcn_mfma_f32_16x16x32_f16(a0h, bh0, acc0[0][0], 0, 0, 0);
            acc0[1][0] = __builtin_amdgcn_mfma_f32_16x16x32_f16(a1h, bh0, acc0[1][0], 0, 0, 0);
            acc0[0][1] = __builtin_amdgcn_mfma_f32_16x16x32_f16(a0h, bh1, acc0[0][1], 0, 0, 0);
            acc0[1][1] = __builtin_amdgcn_mfma_f32_16x16x32_f16(a1h, bh1, acc0[1][1], 0, 0, 0);
            acc1[0][0] = __builtin_amdgcn_mfma_f32_16x16x32_f16(a0l, bh0, acc1[0][0], 0, 0, 0);
            acc1[1][0] = __builtin_amdgcn_mfma_f32_16x16x32_f16(a1l, bh0, acc1[1][0], 0, 0, 0);
            acc1[0][1] = __builtin_amdgcn_mfma_f32_16x16x32_f16(a0l, bh1, acc1[0][1], 0, 0, 0);
            acc1[1][1] = __builtin_amdgcn_mfma_f32_16x16x32_f16(a1l, bh1, acc1[1][1], 0, 0, 0);
            acc1[0][0] = __builtin_amdgcn_mfma_f32_16x16x32_f16(a0h, bl0, acc1[0][0], 0, 0, 0);
            acc1[1][0] = __builtin_amdgcn_mfma_f32_16x16x32_f16(a1h, bl0, acc1[1][0], 0, 0, 0);
            acc1[0][1] = __builtin_amdgcn_mfma_f32_16x16x32_f16(a0h, bl1, acc1[0][1], 0, 0, 0);
            acc1[1][1] = __builtin_amdgcn_mfma_f32_16x16x32_f16(a1h, bl1, acc1[1][1], 0, 0, 0);
            __builtin_amdgcn_s_setprio(0);

            if (t < NTIL - 1) { bh0 = nh0; bh1 = nh1; bl0 = nl0; bl1 = nl1; }
        }
        if (c < NCH - 1) {
            BAR();
#pragma unroll
            for (int s = 0; s < 4; s++) {
                f32x4 v = xr[s];
                f16 h0 = (f16)v.x, h1 = (f16)v.y, h2 = (f16)v.z, h3 = (f16)v.w;
                f16x4 hv = {h0, h1, h2, h3};
                f16x4 lv = {(f16)((v.x - (float)h0) * 2048.0f),
                            (f16)((v.y - (float)h1) * 2048.0f),
                            (f16)((v.z - (float)h2) * 2048.0f),
                            (f16)((v.w - (float)h3) * 2048.0f)};
                *(f16x4*)(AH + wbase + s * 64) = hv;
                *(f16x4*)(AL + wbase + s * 64) = lv;
            }
            BAR();
        }
    }
    __syncthreads();

#pragma unroll
    for (int m = 0; m < 2; m++) {
#pragma unroll
        for (int n = 0; n < 2; n++) {
            const int e = wv * 32 + n * 16 + eb;
            const float b = bias[e];
#pragma unroll
            for (int i = 0; i < 4; i++) {
                const int tk = m * 16 + kq * 4 + i;
                logits[tk][e] = (acc0[m][n][i] + acc1[m][n][i] * (1.0f / 2048.0f)) * (1.0f / 64.0f) + b;
            }
        }
    }
    __syncthreads();

    for (int tt = 0; tt < 4; tt++) {
        const int tok = wv * 4 + tt;
        float4 v4 = *(const float4*)&logits[tok][lane * 4];
        float lv[4] = {v4.x, v4.y, v4.z, v4.w};
        int msk = 0xF;
        float topv[TOPK];
        int   topi[TOPK];
#pragma unroll
        for (int r = 0; r < TOPK; r++) {
            float bvv = -INFINITY;
            int   bii = 0x7fffffff;
#pragma unroll
            for (int j = 0; j < 4; j++) {
                if (msk & (1 << j)) {
                    float vv = lv[j];
                    int   ii = lane * 4 + j;
                    if (vv > bvv || (vv == bvv && ii < bii)) { bvv = vv; bii = ii; }
                }
            }
#pragma unroll
            for (int off = 32; off > 0; off >>= 1) {
                float ov = __shfl_xor(bvv, off);
                int   oi = __shfl_xor(bii, off);
                if (ov > bvv || (ov == bvv && oi < bii)) { bvv = ov; bii = oi; }
            }
            topv[r] = bvv;
            topi[r] = bii;
            if ((bii >> 2) == lane) msk &= ~(1 << (bii & 3));
        }
        float m = topv[0];
        float s = 0.0f;
#pragma unroll
        for (int r = 0; r < TOPK; r++) s += expf(topv[r] - m);

        const int gtok = tok0 + tok;
        if (lane < TOPK) {
            out[(size_t)gtok * TOPK + lane] = expf(topv[lane] - m) / s;
        } else if (lane < 2 * TOPK) {
            int r = lane - TOPK;
            out[(size_t)TOKENS * TOPK + (size_t)gtok * TOPK + r] = (float)topi[r];
            atomicAdd(&hist[topi[r]], 1.0f);
        }
    }
    __syncthreads();
    if (tid < NEXP) {
        float hv = hist[tid];
        if (hv != 0.0f) atomicAdd(&out[(size_t)2 * TOKENS * TOPK + tid], hv);
    }

    if (ctr) {
        __threadfence();
        if (tid == 0) {
            unsigned d = atomicAdd(ctr, 1u);
            lastflag = (d == gridDim.x - 1) ? 1u : 0u;
        }
        __syncthreads();
        if (lastflag) {
            float* counts = out + (size_t)2 * TOKENS * TOPK;
            float c = (tid < NEXP) ? *(volatile float*)&counts[tid] : 0.0f;
            float* sm = hist;
            if (tid < NEXP) sm[tid] = c;
            __syncthreads();
            for (int s = 128; s > 0; s >>= 1) {
                if (tid < s) sm[tid] += sm[tid + s];
                __syncthreads();
            }
            float mean = sm[0] / (float)NEXP;
            __syncthreads();
            if (tid < NEXP) { float d2 = c - mean; sm[tid] = d2 * d2; }
            __syncthreads();
            for (int s = 128; s > 0; s >>= 1) {
                if (tid < s) sm[tid] += sm[tid + s];
                __syncthreads();
            }
            float var = sm[0] / (float)(NEXP - 1);
            __syncthreads();
            if (tid < NEXP) sm[tid] = c;
            __syncthreads();
            for (int s = 128; s > 0; s >>= 1) {
                if (tid < s) sm[tid] = fmaxf(sm[tid], sm[tid + s]);
                __syncthreads();
            }
            float mx = sm[0];
            __syncthreads();
            if (tid < NEXP) sm[tid] = c;
            __syncthreads();
            for (int s = 128; s > 0; s >>= 1) {
                if (tid < s) sm[tid] = fminf(sm[tid], sm[tid + s]);
                __syncthreads();
            }
            float mn = sm[0];
            if (tid == 0) {
                float* scal = counts + NEXP;
                scal[0] = sqrtf(var) / (mean + 1e-6f);
                scal[1] = mx;
                scal[2] = mn;
                scal[3] = (float)(TOKENS * TOPK) / (float)NEXP;
            }
        }
    }
}

// ---------------- fallback (no workspace): fp32 VALU kernel ----------------
__global__ __launch_bounds__(256, 3) void k_main_fb(
        const float* __restrict__ x,
        const float* __restrict__ wsrc,
        const float* __restrict__ bias,
        float* __restrict__ out) {
    __shared__ float xT[16][FBM];
    __shared__ float wS[16][NEXP];
    __shared__ float logits[FBM][NEXP];
    __shared__ float hist[NEXP];

    const int tid  = threadIdx.x;
    const int tok0 = blockIdx.x * FBM;
    const int ty   = tid >> 5;
    const int tx   = tid & 31;

    hist[tid] = 0.0f;

    float acc[4][8];
#pragma unroll
    for (int i = 0; i < 4; i++)
#pragma unroll
        for (int j = 0; j < 8; j++) acc[i][j] = 0.0f;

    const int lx_tok = tid >> 3;
    const int lx_d   = (tid & 7) * 2;

    for (int k0 = 0; k0 < DMODEL; k0 += 16) {
        __syncthreads();
        float2 xv = *(const float2*)&x[(size_t)(tok0 + lx_tok) * DMODEL + k0 + lx_d];
        xT[lx_d][lx_tok]     = xv.x;
        xT[lx_d + 1][lx_tok] = xv.y;
#pragma unroll
        for (int i = 0; i < 16; i++)
            wS[i][tid] = wsrc[(size_t)tid * DMODEL + k0 + i];
        __syncthreads();
#pragma unroll
        for (int k = 0; k < 16; k++) {
            float4 a  = *(const float4*)&xT[k][ty * 4];
            float4 b0 = *(const float4*)&wS[k][tx * 8];
            float4 b1 = *(const float4*)&wS[k][tx * 8 + 4];
            float av[4] = {a.x, a.y, a.z, a.w};
            float bv[8] = {b0.x, b0.y, b0.z, b0.w, b1.x, b1.y, b1.z, b1.w};
#pragma unroll
            for (int i = 0; i < 4; i++)
#pragma unroll
                for (int j = 0; j < 8; j++)
                    acc[i][j] = fmaf(av[i], bv[j], acc[i][j]);
        }
    }

    float bb[8];
#pragma unroll
    for (int j = 0; j < 8; j++) bb[j] = bias[tx * 8 + j];
#pragma unroll
    for (int i = 0; i < 4; i++) {
#pragma unroll
        for (int j = 0; j < 8; j++)
            logits[ty * 4 + i][tx * 8 + j] = acc[i][j] + bb[j];
    }
    __syncthreads();

    const int lane = tid & 63;
    const int wv   = tid >> 6;
    for (int tt = 0; tt < 8; tt++) {
        const int tok = wv * 8 + tt;
        float4 v4 = *(const float4*)&logits[tok][lane * 4];
        float lv[4] = {v4.x, v4.y, v4.z, v4.w};
        int msk = 0xF;
        float topv[TOPK];
        int   topi[TOPK];
#pragma unroll
        for (int r = 0; r < TOPK; r++) {
            float bvv = -INFINITY;
            int   bii = 0x7fffffff;
#pragma unroll
            for (int j = 0; j < 4; j++) {
                if (msk & (1 << j)) {
                    float vv = lv[j];
                    int   ii = lane * 4 + j;
                    if (vv > bvv || (vv == bvv && ii < bii)) { bvv = vv; bii = ii; }
                }
            }
#pragma unroll
            for (int off = 32; off > 0; off >>= 1) {
                float ov = __shfl_xor(bvv, off);
                int   oi = __shfl_xor(bii, off);
                if (ov > bvv || (ov == bvv && oi < bii)) { bvv = ov; bii = oi; }
            }
            topv[r] = bvv;
            topi[r] = bii;
            if ((bii >> 2) == lane) msk &= ~(1 << (bii & 3));
        }
        float m = topv[0];
        float s = 0.0f;
#pragma unroll
        for (int r = 0; r < TOPK; r++) s += expf(topv[r] - m);

        const int gtok = tok0 + tok;
        if (lane < TOPK) {
            out[(size_t)gtok * TOPK + lane] = expf(topv[lane] - m) / s;
        } else if (lane < 2 * TOPK) {
            int r = lane - TOPK;
            out[(size_t)TOKENS * TOPK + (size_t)gtok * TOPK + r] = (float)topi[r];
            atomicAdd(&hist[topi[r]], 1.0f);
        }
    }
    __syncthreads();
    float hv = hist[tid];
    if (hv != 0.0f) atomicAdd(&out[(size_t)2 * TOKENS * TOPK + tid], hv);
}

// ---------------- stats kernel (used when no ctr) ----------------
__global__ void k_stats(float* __restrict__ out) {
    __shared__ float sm[NEXP];
    const float* counts = out + (size_t)2 * TOKENS * TOPK;
    const int t = threadIdx.x;
    float c = counts[t];

    sm[t] = c;
    __syncthreads();
    for (int s = 128; s > 0; s >>= 1) {
        if (t < s) sm[t] += sm[t + s];
        __syncthreads();
    }
    float mean = sm[0] / (float)NEXP;
    __syncthreads();

    float d = c - mean;
    sm[t] = d * d;
    __syncthreads();
    for (int s = 128; s > 0; s >>= 1) {
        if (t < s) sm[t] += sm[t + s];
        __syncthreads();
    }
    float var = sm[0] / (float)(NEXP - 1);
    __syncthreads();

    sm[t] = c;
    __syncthreads();
    for (int s = 128; s > 0; s >>= 1) {
        if (t < s) sm[t] = fmaxf(sm[t], sm[t + s]);
        __syncthreads();
    }
    float mx = sm[0];
    __syncthreads();

    sm[t] = c;
    __syncthreads();
    for (int s = 128; s > 0; s >>= 1) {
        if (t < s) sm[t] = fminf(sm[t], sm[t + s]);
        __syncthreads();
    }
    float mn = sm[0];

    if (t == 0) {
        float* scal = out + (size_t)2 * TOKENS * TOPK + NEXP;
        scal[0] = sqrtf(var) / (mean + 1e-6f);
        scal[1] = mx;
        scal[2] = mn;
        scal[3] = (float)(TOKENS * TOPK) / (float)NEXP;
    }
}

extern "C" void kernel_launch(void* const* d_in, const int* in_sizes, int n_in,
                              void* d_out, int out_size, void* d_ws, size_t ws_size,
                              hipStream_t stream) {
    const float* x    = (const float*)d_in[0];
    const float* w    = (const float*)d_in[1];
    const float* bias = (const float*)d_in[2];
    float* out = (float*)d_out;
    float* counts = out + (size_t)2 * TOKENS * TOPK;

    const size_t need_w  = (size_t)DMODEL * NEXP * 2 * sizeof(f16);             // 2 MB
    const size_t xs_off  = need_w + 64;
    const size_t need_all = xs_off + (size_t)TOKENS * DMODEL * 2 * sizeof(f16); // + 128 MB

    if (ws_size >= need_all) {
        f16* wsH = (f16*)d_ws;
        f16* wsL = wsH + (size_t)DMODEL * NEXP;
        unsigned* ctr = (unsigned*)((char*)d_ws + need_w);
        f16* xs = (f16*)((char*)d_ws + xs_off);
        k_prep<<<(DMODEL * NEXP) / (256 * 8), 256, 0, stream>>>(w, wsH, wsL, counts, ctr);
        k_prep_x<<<(TOKENS / BM) * (NTIL / 2), 256, 0, stream>>>(x, xs);
        k_main<<<TOKENS / BM, 256, 0, stream>>>(xs, wsH, wsL, bias, out, ctr);
    } else if (ws_size >= need_w + 64) {
        f16* wsH = (f16*)d_ws;
        f16* wsL = wsH + (size_t)DMODEL * NEXP;
        unsigned* ctr = (unsigned*)((char*)d_ws + need_w);
        k_prep<<<(DMODEL * NEXP) / (256 * 8), 256, 0, stream>>>(w, wsH, wsL, counts, ctr);
        k_main_lds<<<TOKENS / BM, 512, 0, stream>>>(x, wsH, wsL, bias, out, ctr);
    } else {
        k_zero<<<1, NEXP, 0, stream>>>(counts);
        k_main_fb<<<TOKENS / FBM, 256, 0, stream>>>(x, w, bias, out);
        k_stats<<<1, NEXP, 0, stream>>>(out);
    }
}